// Round 4
// baseline (135.389 us; speedup 1.0000x reference)
//
#include <hip/hip_runtime.h>

#define NB 128
#define NM 60
#define NF 19
#define NA 3
#define NCELL (NF*NF)          // 361
#define NCH 85
#define NCHTOT (NA*NCH)        // 255
#define HALFC 192              // cells per block (half of a (b,a) slice)
#define TPB 384                // 2 groups x 192: grp0 = truths 0..29, grp1 = 30..59
#define NWAVE (TPB/64)         // 6
#define NBLK (NB*NA*2)         // 768

// anchors / 32
__device__ __constant__ float c_aw[9] = {0.3125f, 0.5f, 1.03125f, 0.9375f, 1.9375f, 1.84375f, 3.625f, 4.875f, 11.65625f};
__device__ __constant__ float c_ah[9] = {0.40625f, 0.9375f, 0.71875f, 1.90625f, 1.40625f, 3.71875f, 2.8125f, 6.1875f, 10.1875f};

__device__ __forceinline__ float clog(float v) { return fmaxf(__logf(v), -100.0f); }
__device__ __forceinline__ float sigm(float x) { return 1.0f / (1.0f + __expf(-x)); }

__device__ __forceinline__ float wave_sum(float v) {
    for (int off = 32; off > 0; off >>= 1) v += __shfl_down(v, off, 64);
    return v;
}

// Fully fused: truth prep + winner scatter + per-cell losses (IoU split across
// 2 thread-groups) + wave-cooperative class loop + last-block grid reduction.
__global__ __launch_bounds__(TPB) void k_main(const float* __restrict__ out,
                                              const float* __restrict__ labels,
                                              float* __restrict__ partial,
                                              int* __restrict__ ticket,
                                              float* __restrict__ res) {
    __shared__ float4 s_box[NM];                 // truth x1,y1,x2,y2 (grid units)
    __shared__ float  s_ar[NM];                  // tw*th (1e30 for invalid)
    __shared__ float  s_scale[NM], s_twt[NM], s_tht[NM], s_txf[NM], s_tyf[NM];
    __shared__ int    s_cls[NM];
    __shared__ int    s_win[NCELL];              // winner m per cell (-1 = none)
    __shared__ int    s_ign[HALFC];              // grp1's partial ignore flag
    __shared__ int    s_list[64];                // matched cells: cell | (k<<16)
    __shared__ int    s_n;
    __shared__ int    s_last;
    __shared__ float  s_red[NWAVE][5];

    const int blk  = blockIdx.x;
    const int ba   = blk >> 1;                   // (b, a) slice
    const int half = blk & 1;
    const int b = ba / NA, a = ba % NA;
    const int tid = threadIdx.x;
    const int grp   = (tid >= HALFC) ? 1 : 0;
    const int local = tid - grp * HALFC;
    const int cell  = half * HALFC + local;
    const bool active = cell < NCELL;

    // Early coalesced channel loads (both groups need ch0..3 for the pred box).
    const float* obase = out + ((size_t)b * NCHTOT + a * NCH) * NCELL;
    float r0 = 0.f, r1 = 0.f, r2 = 0.f, r3 = 0.f, r4 = 0.f;
    if (active) {
        r0 = obase[0 * NCELL + cell];
        r1 = obase[1 * NCELL + cell];
        r2 = obase[2 * NCELL + cell];
        r3 = obase[3 * NCELL + cell];
        if (grp == 0) r4 = obase[4 * NCELL + cell];
    }

    for (int c = tid; c < NCELL; c += TPB) s_win[c] = -1;
    if (tid == 0) s_n = 0;
    __syncthreads();   // s_win fully init'd before any atomicMax (round-3 race fix)

    // ---- truth preprocessing (threads 0..59) ----
    if (tid < NM) {
        const float* l = labels + ((size_t)b * NM + tid) * 5;
        float x1 = l[0], y1 = l[1], x2 = l[2], y2 = l[3], cf = l[4];
        bool valid = (x1 + y1 + x2 + y2 + cf) > 0.0f;
        float tx = floorf(x1 * 0.03125f);
        float ty = floorf(y1 * 0.03125f);
        float tw = floorf((x2 - x1) * 0.03125f);
        float th = floorf((y2 - y1) * 0.03125f);
        int ti = (int)tx, tj = (int)ty;
        float bst = -1.0f; int bi = 0;
        #pragma unroll
        for (int q = 0; q < 9; q++) {
            float mw = fminf(tw, c_aw[q]), mh = fminf(th, c_ah[q]);
            float inter = (mw > 0.0f && mh > 0.0f) ? mw * mh : 0.0f;
            float iou = inter / (tw * th + c_aw[q] * c_ah[q] - inter);
            if (iou > bst) { bst = iou; bi = q; }
        }
        int bn = bi % 3;
        // degenerate far-away box + huge area for invalid -> can never ignore
        s_box[tid] = valid ? make_float4(tx - 0.5f * tw, ty - 0.5f * th,
                                         tx + 0.5f * tw, ty + 0.5f * th)
                           : make_float4(3.0e8f, 3.0e8f, 3.0e8f, 3.0e8f);
        s_ar[tid]    = valid ? tw * th : 1.0e30f;
        s_scale[tid] = sqrtf(2.0f - tw * th * (1.0f / (float)NCELL));
        s_twt[tid]   = __logf(tw / c_aw[6 + bn] + 1e-16f);
        s_tht[tid]   = __logf(th / c_ah[6 + bn] + 1e-16f);
        s_txf[tid]   = tx - (float)ti;
        s_tyf[tid]   = ty - (float)tj;
        s_cls[tid]   = (int)cf;
        // last-write-wins == max m (bit-exact vs reference, rounds 1-3)
        if (valid && bi >= 6 && bn == a &&
            ti >= 0 && ti < NF && tj >= 0 && tj < NF) {
            atomicMax(&s_win[tj * NF + ti], tid);
        }
    }
    __syncthreads();

    // ---- per-cell pred box + division-free ignore test over 30 truths ----
    // iou > 0.5  <=>  2*inter > union  <=>  3*inter > parea + area_m
    int ii = cell % NF, jj = cell / NF;
    float sx = sigm(r0), sy = sigm(r1), sobj = sigm(r4);
    float pw = __expf(r2) * c_aw[6 + a], ph = __expf(r3) * c_ah[6 + a];
    float px = sx + (float)ii, py = sy + (float)jj;
    float px1 = px - 0.5f * pw, px2 = px + 0.5f * pw;
    float py1 = py - 0.5f * ph, py2 = py + 0.5f * ph;
    float parea = pw * ph;

    bool ign = false;
    const int mstart = grp * (NM / 2);
    #pragma unroll 6
    for (int m = mstart; m < mstart + NM / 2; m++) {
        float4 tb = s_box[m];
        float dx = fminf(px2, tb.z) - fmaxf(px1, tb.x);
        float dy = fminf(py2, tb.w) - fmaxf(py1, tb.y);
        float inter = fmaxf(dx, 0.0f) * fmaxf(dy, 0.0f);
        ign = ign || (3.0f * inter > parea + s_ar[m]);
    }
    if (grp == 1) s_ign[local] = ign ? 1 : 0;
    __syncthreads();

    // ---- per-cell losses (grp0 only; class term deferred to the list) ----
    float lxy = 0.f, lwh = 0.f, lobj = 0.f, lcls = 0.f, ll2 = 0.f;
    if (grp == 0 && active) {
        ign = ign || (s_ign[local] != 0);
        int w = s_win[cell];
        if (w >= 0) {
            float s = s_scale[w], s2 = s * s;
            float txf = s_txf[w], tyf = s_tyf[w];
            float dw = r2 - s_twt[w], dh = r3 - s_tht[w];
            lxy = -s2 * (txf * clog(sx) + (1.0f - txf) * clog(1.0f - sx)
                       + tyf * clog(sy) + (1.0f - tyf) * clog(1.0f - sy));
            float whsq = s2 * (dw * dw + dh * dh);
            lwh = 0.5f * whsq;
            lobj = -clog(sobj);
            ll2 = (sx - txf) * (sx - txf) + (sy - tyf) * (sy - tyf)
                + whsq + (sobj - 1.0f) * (sobj - 1.0f);
            int pos = atomicAdd(&s_n, 1);
            s_list[pos] = cell | (s_cls[w] << 16);
        } else if (!ign) {
            lobj = -clog(1.0f - sobj);
            ll2 = sobj * sobj;
        }
    }
    __syncthreads();

    // ---- cooperative class loop: wave per entry, lane per channel ----
    int nlist = s_n;
    int lane = tid & 63, wid = tid >> 6;
    for (int e = wid; e < nlist; e += NWAVE) {
        int packed = s_list[e];
        int mc = packed & 0xFFFF, k = packed >> 16;
        const float* p = obase + (size_t)5 * NCELL + mc;
        {
            float sc = sigm(p[(size_t)lane * NCELL]);
            bool isk = (lane == k);
            lcls -= isk ? clog(sc) : clog(1.0f - sc);
            float d = isk ? (sc - 1.0f) : sc;
            ll2 += d * d;
        }
        if (lane < 16) {
            int c2 = lane + 64;
            float sc = sigm(p[(size_t)c2 * NCELL]);
            bool isk = (c2 == k);
            lcls -= isk ? clog(sc) : clog(1.0f - sc);
            float d = isk ? (sc - 1.0f) : sc;
            ll2 += d * d;
        }
    }

    // ---- block reduce -> partial store -> last-block grid reduction ----
    float v0 = wave_sum(lxy), v1 = wave_sum(lwh), v2 = wave_sum(lobj);
    float v3 = wave_sum(lcls), v4 = wave_sum(ll2);
    if (lane == 0) {
        s_red[wid][0] = v0; s_red[wid][1] = v1; s_red[wid][2] = v2;
        s_red[wid][3] = v3; s_red[wid][4] = v4;
    }
    __syncthreads();
    if (tid == 0) {
        float t0 = 0.f, t1 = 0.f, t2 = 0.f, t3 = 0.f, t4 = 0.f;
        #pragma unroll
        for (int wv = 0; wv < NWAVE; wv++) {
            t0 += s_red[wv][0]; t1 += s_red[wv][1]; t2 += s_red[wv][2];
            t3 += s_red[wv][3]; t4 += s_red[wv][4];
        }
        float* pb = partial + (size_t)blk * 5;
        pb[0] = t0; pb[1] = t1; pb[2] = t2; pb[3] = t3; pb[4] = t4;
        __threadfence();   // release partials to device scope
        int old = __hip_atomic_fetch_add(ticket, 1, __ATOMIC_ACQ_REL,
                                         __HIP_MEMORY_SCOPE_AGENT);
        s_last = (old == NBLK - 1) ? 1 : 0;
    }
    __syncthreads();
    if (s_last) {
        __threadfence();   // acquire: invalidate caches before reading partials
        float a0 = 0.f, a1 = 0.f, a2 = 0.f, a3 = 0.f, a4 = 0.f;
        for (int i = tid; i < NBLK; i += TPB) {
            const float* p = partial + (size_t)i * 5;
            a0 += p[0]; a1 += p[1]; a2 += p[2]; a3 += p[3]; a4 += p[4];
        }
        a0 = wave_sum(a0); a1 = wave_sum(a1); a2 = wave_sum(a2);
        a3 = wave_sum(a3); a4 = wave_sum(a4);
        if (lane == 0) {
            s_red[wid][0] = a0; s_red[wid][1] = a1; s_red[wid][2] = a2;
            s_red[wid][3] = a3; s_red[wid][4] = a4;
        }
        __syncthreads();
        if (tid == 0) {
            float t[5];
            #pragma unroll
            for (int j = 0; j < 5; j++) {
                float s = 0.f;
                #pragma unroll
                for (int wv = 0; wv < NWAVE; wv++) s += s_red[wv][j];
                t[j] = s;
            }
            res[0] = t[0] + t[1] + t[2] + t[3];
            res[1] = t[0]; res[2] = t[1]; res[3] = t[2];
            res[4] = t[3]; res[5] = t[4];
        }
    }
}

extern "C" void kernel_launch(void* const* d_in, const int* in_sizes, int n_in,
                              void* d_out, int out_size, void* d_ws, size_t ws_size,
                              hipStream_t stream) {
    (void)in_sizes; (void)n_in; (void)out_size; (void)ws_size;
    const float* output = (const float*)d_in[0];
    const float* labels = (const float*)d_in[1];
    float* res = (float*)d_out;
    int*   ticket  = (int*)d_ws;                     // 1 int, zeroed per call
    float* partial = (float*)((char*)d_ws + 64);     // NBLK*5 floats

    hipMemsetAsync(ticket, 0, sizeof(int), stream);
    k_main<<<NBLK, TPB, 0, stream>>>(output, labels, partial, ticket, res);
}

// Round 6
// 91.294 us; speedup vs baseline: 1.4830x; 1.4830x over previous
//
#include <hip/hip_runtime.h>

#define NB 128
#define NM 60
#define NF 19
#define NA 3
#define NCELL (NF*NF)          // 361
#define NCH 85
#define NCHTOT (NA*NCH)        // 255
#define HALFC 192              // cells per block (half of a (b,a) slice)
#define TPB 384                // 2 groups x 192: grp0 = truths 0..29, grp1 = 30..59
#define NWAVE (TPB/64)         // 6
#define NBLK (NB*NA*2)         // 768
#define MAXLIST 64

// anchors / 32
__device__ __constant__ float c_aw[9] = {0.3125f, 0.5f, 1.03125f, 0.9375f, 1.9375f, 1.84375f, 3.625f, 4.875f, 11.65625f};
__device__ __constant__ float c_ah[9] = {0.40625f, 0.9375f, 0.71875f, 1.90625f, 1.40625f, 3.71875f, 2.8125f, 6.1875f, 10.1875f};

__device__ __forceinline__ float clog(float v) { return fmaxf(__logf(v), -100.0f); }
__device__ __forceinline__ float sigm(float x) { return 1.0f / (1.0f + __expf(-x)); }

__device__ __forceinline__ float wave_sum(float v) {
    for (int off = 32; off > 0; off >>= 1) v += __shfl_down(v, off, 64);
    return v;
}

// Fused: truth prep + winner scatter + per-cell losses (IoU split across 2
// thread-groups) + flattened class gather + contention-free partial store.
// NOTE (round 4 lesson): NO device-scope fences here — per-block
// buffer_wbl2/buffer_inv serialized at the XCD L2s and cost ~40 us wall.
__global__ __launch_bounds__(TPB) void k_main(const float* __restrict__ out,
                                              const float* __restrict__ labels,
                                              float* __restrict__ partial) {
    __shared__ float4 s_box[NM];                 // truth x1,y1,x2,y2 (grid units)
    __shared__ float  s_ar[NM];                  // tw*th (1e30 for invalid)
    __shared__ float  s_scale[NM], s_twt[NM], s_tht[NM], s_txf[NM], s_tyf[NM];
    __shared__ int    s_cls[NM];
    __shared__ int    s_win[NCELL];              // winner m per cell (-1 = none)
    __shared__ int    s_ign[HALFC];              // grp1's partial ignore flag
    __shared__ int    s_list[MAXLIST];           // matched cells: cell | (k<<16)
    __shared__ int    s_n;
    __shared__ float  s_red[NWAVE][5];

    const int blk  = blockIdx.x;
    const int ba   = blk >> 1;                   // (b, a) slice
    const int half = blk & 1;
    const int b = ba / NA, a = ba % NA;
    const int tid = threadIdx.x;
    const int grp   = (tid >= HALFC) ? 1 : 0;
    const int local = tid - grp * HALFC;
    const int cell  = half * HALFC + local;
    const bool active = cell < NCELL;

    // ---- issue BOTH cold-load chains up front (labels first: needed first) ----
    float x1 = 0.f, y1 = 0.f, x2 = 0.f, y2 = 0.f, cf = 0.f;
    if (tid < NM) {
        const float* l = labels + ((size_t)b * NM + tid) * 5;
        x1 = l[0]; y1 = l[1]; x2 = l[2]; y2 = l[3]; cf = l[4];
    }
    const float* obase = out + ((size_t)b * NCHTOT + a * NCH) * NCELL;
    float r0 = 0.f, r1 = 0.f, r2 = 0.f, r3 = 0.f, r4 = 0.f;
    if (active) {
        r0 = obase[0 * NCELL + cell];
        r1 = obase[1 * NCELL + cell];
        r2 = obase[2 * NCELL + cell];
        r3 = obase[3 * NCELL + cell];
        if (grp == 0) r4 = obase[4 * NCELL + cell];
    }

    for (int c = tid; c < NCELL; c += TPB) s_win[c] = -1;
    if (tid == 0) s_n = 0;
    __syncthreads();   // s_win fully init'd before any atomicMax

    // ---- truth preprocessing (threads 0..59) ----
    if (tid < NM) {
        bool valid = (x1 + y1 + x2 + y2 + cf) > 0.0f;
        float tx = floorf(x1 * 0.03125f);
        float ty = floorf(y1 * 0.03125f);
        float tw = floorf((x2 - x1) * 0.03125f);
        float th = floorf((y2 - y1) * 0.03125f);
        int ti = (int)tx, tj = (int)ty;
        float bst = -1.0f; int bi = 0;
        #pragma unroll
        for (int q = 0; q < 9; q++) {
            float mw = fminf(tw, c_aw[q]), mh = fminf(th, c_ah[q]);
            float inter = (mw > 0.0f && mh > 0.0f) ? mw * mh : 0.0f;
            float iou = inter / (tw * th + c_aw[q] * c_ah[q] - inter);
            if (iou > bst) { bst = iou; bi = q; }
        }
        int bn = bi % 3;
        // degenerate far-away box + huge area for invalid -> can never ignore
        s_box[tid] = valid ? make_float4(tx - 0.5f * tw, ty - 0.5f * th,
                                         tx + 0.5f * tw, ty + 0.5f * th)
                           : make_float4(3.0e8f, 3.0e8f, 3.0e8f, 3.0e8f);
        s_ar[tid]    = valid ? tw * th : 1.0e30f;
        s_scale[tid] = sqrtf(2.0f - tw * th * (1.0f / (float)NCELL));
        s_twt[tid]   = __logf(tw / c_aw[6 + bn] + 1e-16f);
        s_tht[tid]   = __logf(th / c_ah[6 + bn] + 1e-16f);
        s_txf[tid]   = tx - (float)ti;
        s_tyf[tid]   = ty - (float)tj;
        s_cls[tid]   = (int)cf;
        // last-write-wins == max m (bit-exact vs reference, rounds 1-4)
        if (valid && bi >= 6 && bn == a &&
            ti >= 0 && ti < NF && tj >= 0 && tj < NF) {
            atomicMax(&s_win[tj * NF + ti], tid);
        }
    }
    __syncthreads();

    // ---- per-cell pred box + division-free ignore test over 30 truths ----
    // iou > 0.5  <=>  3*inter > parea + area_m   (validated bit-exact round 4)
    int ii = cell % NF, jj = cell / NF;
    float sx = sigm(r0), sy = sigm(r1), sobj = sigm(r4);
    float pw = __expf(r2) * c_aw[6 + a], ph = __expf(r3) * c_ah[6 + a];
    float px = sx + (float)ii, py = sy + (float)jj;
    float px1 = px - 0.5f * pw, px2 = px + 0.5f * pw;
    float py1 = py - 0.5f * ph, py2 = py + 0.5f * ph;
    float parea = pw * ph;

    bool ign = false;
    const int mstart = grp * (NM / 2);
    #pragma unroll 6
    for (int m = mstart; m < mstart + NM / 2; m++) {
        float4 tb = s_box[m];
        float dx = fminf(px2, tb.z) - fmaxf(px1, tb.x);
        float dy = fminf(py2, tb.w) - fmaxf(py1, tb.y);
        float inter = fmaxf(dx, 0.0f) * fmaxf(dy, 0.0f);
        ign = ign || (3.0f * inter > parea + s_ar[m]);
    }
    if (grp == 1) s_ign[local] = ign ? 1 : 0;
    __syncthreads();

    // ---- per-cell losses (grp0 only; class term deferred to the list) ----
    float lxy = 0.f, lwh = 0.f, lobj = 0.f, lcls = 0.f, ll2 = 0.f;
    if (grp == 0 && active) {
        ign = ign || (s_ign[local] != 0);
        int w = s_win[cell];
        if (w >= 0) {
            float s = s_scale[w], s2 = s * s;
            float txf = s_txf[w], tyf = s_tyf[w];
            float dw = r2 - s_twt[w], dh = r3 - s_tht[w];
            lxy = -s2 * (txf * clog(sx) + (1.0f - txf) * clog(1.0f - sx)
                       + tyf * clog(sy) + (1.0f - tyf) * clog(1.0f - sy));
            float whsq = s2 * (dw * dw + dh * dh);
            lwh = 0.5f * whsq;
            lobj = -clog(sobj);
            ll2 = (sx - txf) * (sx - txf) + (sy - tyf) * (sy - tyf)
                + whsq + (sobj - 1.0f) * (sobj - 1.0f);
            int pos = atomicAdd(&s_n, 1);
            if (pos < MAXLIST) s_list[pos] = cell | (s_cls[w] << 16);
        } else if (!ign) {
            lobj = -clog(1.0f - sobj);
            ll2 = sobj * sobj;
        }
    }
    __syncthreads();

    // ---- flattened class gather: worker w -> (entry e, channel c) ----
    int nwork = min(s_n, MAXLIST) * 96;
    for (int w = tid; w < nwork; w += TPB) {
        int e = w / 96;                       // magic-mul, cheap
        int c = w - e * 96;
        if (c < 80) {
            int packed = s_list[e];
            int mc = packed & 0xFFFF, k = packed >> 16;
            float sc = sigm(obase[(size_t)(5 + c) * NCELL + mc]);
            bool isk = (c == k);
            lcls -= isk ? clog(sc) : clog(1.0f - sc);
            float d = isk ? (sc - 1.0f) : sc;
            ll2 += d * d;
        }
    }

    // ---- block reduce -> contention-free partial store ----
    float v0 = wave_sum(lxy), v1 = wave_sum(lwh), v2 = wave_sum(lobj);
    float v3 = wave_sum(lcls), v4 = wave_sum(ll2);
    int lane = tid & 63, wid = tid >> 6;
    if (lane == 0) {
        s_red[wid][0] = v0; s_red[wid][1] = v1; s_red[wid][2] = v2;
        s_red[wid][3] = v3; s_red[wid][4] = v4;
    }
    __syncthreads();
    if (tid < 5) {
        float s = 0.0f;
        #pragma unroll
        for (int wv = 0; wv < NWAVE; wv++) s += s_red[wv][tid];
        partial[(size_t)blk * 5 + tid] = s;
    }
}

__global__ __launch_bounds__(256) void k_reduce(const float* __restrict__ partial,
                                                float* __restrict__ res) {
    __shared__ float s[4][5];
    int tid = threadIdx.x;
    float acc[5] = {0.f, 0.f, 0.f, 0.f, 0.f};
    for (int i = tid; i < NBLK; i += 256) {
        const float* p = partial + (size_t)i * 5;
        acc[0] += p[0]; acc[1] += p[1]; acc[2] += p[2];
        acc[3] += p[3]; acc[4] += p[4];
    }
    #pragma unroll
    for (int j = 0; j < 5; j++) acc[j] = wave_sum(acc[j]);
    int lane = tid & 63, wid = tid >> 6;
    if (lane == 0) {
        #pragma unroll
        for (int j = 0; j < 5; j++) s[wid][j] = acc[j];
    }
    __syncthreads();
    if (tid == 0) {
        float t[5];
        #pragma unroll
        for (int j = 0; j < 5; j++) t[j] = s[0][j] + s[1][j] + s[2][j] + s[3][j];
        res[0] = t[0] + t[1] + t[2] + t[3];
        res[1] = t[0]; res[2] = t[1]; res[3] = t[2];
        res[4] = t[3]; res[5] = t[4];
    }
}

extern "C" void kernel_launch(void* const* d_in, const int* in_sizes, int n_in,
                              void* d_out, int out_size, void* d_ws, size_t ws_size,
                              hipStream_t stream) {
    (void)in_sizes; (void)n_in; (void)out_size; (void)ws_size;
    const float* output = (const float*)d_in[0];
    const float* labels = (const float*)d_in[1];
    float* res = (float*)d_out;
    float* partial = (float*)d_ws;               // NBLK*5 floats

    k_main<<<NBLK, TPB, 0, stream>>>(output, labels, partial);
    k_reduce<<<1, 256, 0, stream>>>(partial, res);
}